// Round 1
// baseline (2767.109 us; speedup 1.0000x reference)
//
#include <hip/hip_runtime.h>
#include <math.h>

constexpr int R = 128, C = 256, E = 768, H = 12, DK = 64;
constexpr int M = R * C;                 // 32768 tokens
constexpr size_t TOK = (size_t)M * E;    // 25165824 elems per q/k/v/c buffer

// ---------------------------------------------------------------------------
// Projection GEMM: Y[m,n] = (sum_k X[m,k]*W[n,k] + b[n]) * scale
// M=32768, N=768, K=768.  BM=BN=64, BK=16, 256 threads, 4x4 microtile.
// ---------------------------------------------------------------------------
__global__ __launch_bounds__(256) void proj_gemm(
    const float* __restrict__ X, const float* __restrict__ W,
    const float* __restrict__ b, float* __restrict__ Y, float scale) {
  __shared__ float As[16][64];   // [k][m]
  __shared__ float Bs[16][64];   // [k][n]
  const int tid = threadIdx.x;
  const int tx = tid & 15, ty = tid >> 4;
  const int m0 = blockIdx.y * 64, n0 = blockIdx.x * 64;
  const int lr = tid >> 2;          // row within 64-row tile
  const int lc = (tid & 3) * 4;     // col within 16-col k-tile
  float acc[4][4] = {};
  for (int k0 = 0; k0 < E; k0 += 16) {
    float4 a4 = *(const float4*)(X + (size_t)(m0 + lr) * E + k0 + lc);
    float4 b4 = *(const float4*)(W + (size_t)(n0 + lr) * E + k0 + lc);
    __syncthreads();
    As[lc+0][lr]=a4.x; As[lc+1][lr]=a4.y; As[lc+2][lr]=a4.z; As[lc+3][lr]=a4.w;
    Bs[lc+0][lr]=b4.x; Bs[lc+1][lr]=b4.y; Bs[lc+2][lr]=b4.z; Bs[lc+3][lr]=b4.w;
    __syncthreads();
#pragma unroll
    for (int kk = 0; kk < 16; ++kk) {
      float4 a  = *(float4*)&As[kk][ty*4];
      float4 bb = *(float4*)&Bs[kk][tx*4];
      float av[4] = {a.x, a.y, a.z, a.w};
      float bv[4] = {bb.x, bb.y, bb.z, bb.w};
#pragma unroll
      for (int i = 0; i < 4; ++i)
#pragma unroll
        for (int j = 0; j < 4; ++j) acc[i][j] += av[i] * bv[j];
    }
  }
  float4 bb4 = *(const float4*)(b + n0 + tx*4);
  float bvv[4] = {bb4.x, bb4.y, bb4.z, bb4.w};
#pragma unroll
  for (int i = 0; i < 4; ++i) {
    float4 o;
    o.x = (acc[i][0] + bvv[0]) * scale;
    o.y = (acc[i][1] + bvv[1]) * scale;
    o.z = (acc[i][2] + bvv[2]) * scale;
    o.w = (acc[i][3] + bvv[3]) * scale;
    *(float4*)(Y + (size_t)(m0 + ty*4 + i) * E + n0 + tx*4) = o;
  }
}

// ---------------------------------------------------------------------------
// Tied-row scores: S[h,i,j] = sum_{r,d} q[r,i,h,d] * k[r,j,h,d]
// 32x32 (i,j) tile per block, loop r=0..127, d-depth 64.  2x2 microtile.
// ---------------------------------------------------------------------------
__global__ __launch_bounds__(256) void qk_scores(
    const float* __restrict__ q, const float* __restrict__ k,
    float* __restrict__ S) {
  __shared__ float Qs[32][68];   // pad 68 (272B rows: 16B aligned, banks spread)
  __shared__ float Ks[32][68];
  const int h  = blockIdx.z;
  const int i0 = blockIdx.x * 32, j0 = blockIdx.y * 32;
  const int tid = threadIdx.x;
  const int tx = tid & 15, ty = tid >> 4;
  float a00 = 0.f, a01 = 0.f, a10 = 0.f, a11 = 0.f;
  for (int r = 0; r < R; ++r) {
    __syncthreads();
#pragma unroll
    for (int t = 0; t < 2; ++t) {
      int idx = t * 256 + tid;           // 512 float4 per tile pair of rows
      int row = idx >> 4;                // 0..31
      int c4  = (idx & 15) * 4;          // 0..60
      *(float4*)&Qs[row][c4] =
          *(const float4*)(q + (size_t)(r*C + i0 + row) * E + h*DK + c4);
      *(float4*)&Ks[row][c4] =
          *(const float4*)(k + (size_t)(r*C + j0 + row) * E + h*DK + c4);
    }
    __syncthreads();
#pragma unroll
    for (int d4 = 0; d4 < 16; ++d4) {
      float4 qa = *(float4*)&Qs[ty*2+0][d4*4];
      float4 qb = *(float4*)&Qs[ty*2+1][d4*4];
      float4 ka = *(float4*)&Ks[tx*2+0][d4*4];
      float4 kb = *(float4*)&Ks[tx*2+1][d4*4];
      a00 += qa.x*ka.x + qa.y*ka.y + qa.z*ka.z + qa.w*ka.w;
      a01 += qa.x*kb.x + qa.y*kb.y + qa.z*kb.z + qa.w*kb.w;
      a10 += qb.x*ka.x + qb.y*ka.y + qb.z*ka.z + qb.w*ka.w;
      a11 += qb.x*kb.x + qb.y*kb.y + qb.z*kb.z + qb.w*kb.w;
    }
  }
  const int i = i0 + ty*2, j = j0 + tx*2;
  S[((size_t)h*C + i    )*C + j    ] = a00;
  S[((size_t)h*C + i    )*C + j + 1] = a01;
  S[((size_t)h*C + i + 1)*C + j    ] = a10;
  S[((size_t)h*C + i + 1)*C + j + 1] = a11;
}

// ---------------------------------------------------------------------------
// Row softmax over 256 elements, in place.  One block (256 thr) per row.
// ---------------------------------------------------------------------------
__global__ __launch_bounds__(256) void softmax_rows(float* __restrict__ S) {
  const size_t row = blockIdx.x;
  const int tid = threadIdx.x;
  float x = S[row * 256 + tid];
  float m = x;
#pragma unroll
  for (int o = 32; o > 0; o >>= 1) m = fmaxf(m, __shfl_xor(m, o));
  __shared__ float sm[4], ss[4];
  const int wid = tid >> 6, lane = tid & 63;
  if (lane == 0) sm[wid] = m;
  __syncthreads();
  m = fmaxf(fmaxf(sm[0], sm[1]), fmaxf(sm[2], sm[3]));
  float e = expf(x - m);
  float s = e;
#pragma unroll
  for (int o = 32; o > 0; o >>= 1) s += __shfl_xor(s, o);
  if (lane == 0) ss[wid] = s;
  __syncthreads();
  s = ss[0] + ss[1] + ss[2] + ss[3];
  S[row * 256 + tid] = e / s;
}

// ---------------------------------------------------------------------------
// PV: c[r,i,h,d] = sum_j P[h,i,j] * v[r,j,h,d]
// Per block: fixed (h, r), 64-i tile x 64-d, K=j=256 in 16-chunks. 4x4 microtile.
// ---------------------------------------------------------------------------
__global__ __launch_bounds__(256) void pv_gemm(
    const float* __restrict__ P, const float* __restrict__ V,
    float* __restrict__ Cc) {
  __shared__ float Ps[16][64];   // [j][i]
  __shared__ float Vs[16][64];   // [j][d]
  const int i0 = blockIdx.x * 64;
  const int r  = blockIdx.y;
  const int h  = blockIdx.z;
  const int tid = threadIdx.x;
  const int tx = tid & 15, ty = tid >> 4;
  const int plr = tid >> 2;         // i-offset 0..63
  const int plc = (tid & 3) * 4;    // j-offset {0,4,8,12}
  const int vj  = tid >> 4;         // 0..15
  const int vd  = (tid & 15) * 4;   // 0..60
  float acc[4][4] = {};
  for (int j0 = 0; j0 < C; j0 += 16) {
    float4 p4 = *(const float4*)(P + ((size_t)h*C + i0 + plr) * C + j0 + plc);
    float4 v4 = *(const float4*)(V + (size_t)(r*C + j0 + vj) * E + h*DK + vd);
    __syncthreads();
    Ps[plc+0][plr]=p4.x; Ps[plc+1][plr]=p4.y; Ps[plc+2][plr]=p4.z; Ps[plc+3][plr]=p4.w;
    *(float4*)&Vs[vj][vd] = v4;
    __syncthreads();
#pragma unroll
    for (int jj = 0; jj < 16; ++jj) {
      float4 a = *(float4*)&Ps[jj][ty*4];
      float4 b = *(float4*)&Vs[jj][tx*4];
      float av[4] = {a.x, a.y, a.z, a.w};
      float bv[4] = {b.x, b.y, b.z, b.w};
#pragma unroll
      for (int ii = 0; ii < 4; ++ii)
#pragma unroll
        for (int dd = 0; dd < 4; ++dd) acc[ii][dd] += av[ii] * bv[dd];
    }
  }
#pragma unroll
  for (int ii = 0; ii < 4; ++ii) {
    float4 o = make_float4(acc[ii][0], acc[ii][1], acc[ii][2], acc[ii][3]);
    *(float4*)(Cc + (size_t)(r*C + i0 + ty*4 + ii) * E + h*DK + tx*4) = o;
  }
}

// ---------------------------------------------------------------------------
extern "C" void kernel_launch(void* const* d_in, const int* in_sizes, int n_in,
                              void* d_out, int out_size, void* d_ws, size_t ws_size,
                              hipStream_t stream) {
  const float* x  = (const float*)d_in[0];
  const float* Wq = (const float*)d_in[1];
  const float* bq = (const float*)d_in[2];
  const float* Wk = (const float*)d_in[3];
  const float* bk = (const float*)d_in[4];
  const float* Wv = (const float*)d_in[5];
  const float* bv = (const float*)d_in[6];
  const float* Wo = (const float*)d_in[7];
  const float* bo = (const float*)d_in[8];

  float* out   = (float*)d_out;            // (R,C,1,E) = 25165824 floats
  float* probs = out + TOK;                // (H,1,C,C) =   786432 floats

  float* ws = (float*)d_ws;                // needs 3*TOK floats = 302 MB
  float* q  = ws;
  float* k  = ws + TOK;
  float* v  = ws + 2 * TOK;
  float* c  = q;                           // q dead after qk_scores -> reuse

  const float scaling = (float)(0.125 / sqrt(128.0));  // Dk^-0.5 / sqrt(R)

  dim3 gProj(E / 64, M / 64);              // (12, 512)
  proj_gemm<<<gProj, 256, 0, stream>>>(x, Wq, bq, q, scaling);
  proj_gemm<<<gProj, 256, 0, stream>>>(x, Wk, bk, k, 1.0f);
  proj_gemm<<<gProj, 256, 0, stream>>>(x, Wv, bv, v, 1.0f);

  qk_scores<<<dim3(C / 32, C / 32, H), 256, 0, stream>>>(q, k, probs);
  softmax_rows<<<H * C, 256, 0, stream>>>(probs);
  pv_gemm<<<dim3(C / 64, R, H), 256, 0, stream>>>(probs, v, c);

  proj_gemm<<<gProj, 256, 0, stream>>>(c, Wo, bo, out, 1.0f);
}

// Round 2
// 539.754 us; speedup vs baseline: 5.1266x; 5.1266x over previous
//
#include <hip/hip_runtime.h>
#include <math.h>

typedef short bf16x8 __attribute__((ext_vector_type(8)));
typedef float f32x4 __attribute__((ext_vector_type(4)));
typedef unsigned short ushort8 __attribute__((ext_vector_type(8)));

constexpr int R = 128, Cc = 256, E = 768, H = 12;
constexpr int M = R * Cc;                 // 32768 tokens
constexpr size_t TOK = (size_t)M * E;     // 25165824

// fp32 -> bf16 round-to-nearest-even
__device__ __forceinline__ unsigned short f2b(float f) {
  unsigned int u = __float_as_uint(f);
  u += 0x7fff + ((u >> 16) & 1);
  return (unsigned short)(u >> 16);
}

// async global->LDS, 16B per lane. LDS dest must be wave-uniform base + lane*16.
__device__ __forceinline__ void ldst16(const unsigned short* g, unsigned short* l) {
  __builtin_amdgcn_global_load_lds(
      (const __attribute__((address_space(1))) unsigned int*)g,
      (__attribute__((address_space(3))) unsigned int*)l, 16, 0, 0);
}

// ---------------------------------------------------------------------------
__global__ __launch_bounds__(256) void cvt_bf16(const float* __restrict__ in,
                                                unsigned short* __restrict__ out,
                                                int n8) {
  int i = blockIdx.x * 256 + threadIdx.x;
  if (i >= n8) return;
  const float4* p = (const float4*)in;
  float4 a = p[2 * i], b = p[2 * i + 1];
  ushort8 o;
  o[0] = f2b(a.x); o[1] = f2b(a.y); o[2] = f2b(a.z); o[3] = f2b(a.w);
  o[4] = f2b(b.x); o[5] = f2b(b.y); o[6] = f2b(b.z); o[7] = f2b(b.w);
  ((ushort8*)out)[i] = o;
}

// ---------------------------------------------------------------------------
// Projection GEMM (m97 structure): Y = (A[MxK] * B[NxK]^T + bias) * scale
// 128x128 tile, BK=32, 256 thr (4 waves, each 64x64 = 4x4 MFMAs of 16x16x32).
// MODE 0: bf16 row-major [M][N]; MODE 1: bf16 transposed [N][M]; MODE 2: fp32 [M][N]
// ---------------------------------------------------------------------------
template <int MODE>
__global__ __launch_bounds__(256) void proj_mfma(
    const unsigned short* __restrict__ A, const unsigned short* __restrict__ B,
    const float* __restrict__ bias, void* __restrict__ Yv, float scale) {
  constexpr int K = 768, N = 768;
  __shared__ unsigned short As[128 * 32];
  __shared__ unsigned short Bs[128 * 32];
  const int tid = threadIdx.x, wv = tid >> 6, ln = tid & 63;
  const int n0 = blockIdx.x * 128, m0 = blockIdx.y * 128;
  const int wm = (wv & 1) * 64, wn = (wv >> 1) * 64;
  const int srow = ln >> 2, scol = (ln & 3) * 8;  // 4 lanes x 16B per 64B row
  f32x4 acc[4][4] = {};
  for (int k0 = 0; k0 < K; k0 += 32) {
    __syncthreads();
#pragma unroll
    for (int t = 0; t < 2; ++t) {
      const int ch = wv * 2 + t;       // 8 chunks of 1024B per 8KB tile
      const int row = ch * 16 + srow;
      ldst16(A + (size_t)(m0 + row) * K + k0 + scol, As + ch * 512 + ln * 8);
      ldst16(B + (size_t)(n0 + row) * K + k0 + scol, Bs + ch * 512 + ln * 8);
    }
    __syncthreads();
    bf16x8 a[4], b[4];
#pragma unroll
    for (int i = 0; i < 4; ++i)
      a[i] = *(const bf16x8*)(As + (wm + i * 16 + (ln & 15)) * 32 + (ln >> 4) * 8);
#pragma unroll
    for (int j = 0; j < 4; ++j)
      b[j] = *(const bf16x8*)(Bs + (wn + j * 16 + (ln & 15)) * 32 + (ln >> 4) * 8);
#pragma unroll
    for (int i = 0; i < 4; ++i)
#pragma unroll
      for (int j = 0; j < 4; ++j)
        acc[i][j] = __builtin_amdgcn_mfma_f32_16x16x32_bf16(a[i], b[j], acc[i][j], 0, 0, 0);
  }
#pragma unroll
  for (int j = 0; j < 4; ++j) {
    const int n = n0 + wn + j * 16 + (ln & 15);
    const float bn = bias[n];
#pragma unroll
    for (int i = 0; i < 4; ++i) {
#pragma unroll
      for (int r = 0; r < 4; ++r) {
        const int m = m0 + wm + i * 16 + (ln >> 4) * 4 + r;
        const float v = (acc[i][j][r] + bn) * scale;
        if (MODE == 0)      ((unsigned short*)Yv)[(size_t)m * N + n] = f2b(v);
        else if (MODE == 1) ((unsigned short*)Yv)[(size_t)n * M + m] = f2b(v);
        else                ((float*)Yv)[(size_t)m * N + n] = v;
      }
    }
  }
}

// ---------------------------------------------------------------------------
// Tied scores as GEMM: S[h,i,j] = sum_{r,d} q[r,i,h,d]*k[r,j,h,d]
// Per block: 64x64 (i,j) tile of one head, K-chunk = 32 r-values (K=2048).
// 4 waves 2x2, each 32x32. Partials to Sp[kc][h][i][j].
// ---------------------------------------------------------------------------
__global__ __launch_bounds__(256) void qk_mfma(const unsigned short* __restrict__ q,
                                               const unsigned short* __restrict__ k,
                                               float* __restrict__ Sp) {
  __shared__ unsigned short As[64 * 64];
  __shared__ unsigned short Bs[64 * 64];
  const int tid = threadIdx.x, wv = tid >> 6, ln = tid & 63;
  const int i0 = (blockIdx.x & 3) * 64, j0 = (blockIdx.x >> 2) * 64;
  const int h = blockIdx.y, kc = blockIdx.z;
  const int wm = (wv & 1) * 32, wn = (wv >> 1) * 32;
  const int srow = ln >> 3, scol = (ln & 7) * 8;  // 8 lanes x 16B per 128B row
  f32x4 acc[2][2] = {};
  for (int rr = 0; rr < 32; ++rr) {
    const int r = kc * 32 + rr;
    __syncthreads();
#pragma unroll
    for (int t = 0; t < 2; ++t) {
      const int ch = wv * 2 + t;       // 8 chunks per 8KB (64x64 bf16) tile
      const int row = ch * 8 + srow;
      ldst16(q + (size_t)(r * Cc + i0 + row) * E + h * 64 + scol, As + ch * 512 + ln * 8);
      ldst16(k + (size_t)(r * Cc + j0 + row) * E + h * 64 + scol, Bs + ch * 512 + ln * 8);
    }
    __syncthreads();
#pragma unroll
    for (int dk = 0; dk < 2; ++dk) {
      bf16x8 a[2], b[2];
#pragma unroll
      for (int i = 0; i < 2; ++i)
        a[i] = *(const bf16x8*)(As + (wm + i * 16 + (ln & 15)) * 64 + dk * 32 + (ln >> 4) * 8);
#pragma unroll
      for (int j = 0; j < 2; ++j)
        b[j] = *(const bf16x8*)(Bs + (wn + j * 16 + (ln & 15)) * 64 + dk * 32 + (ln >> 4) * 8);
#pragma unroll
      for (int i = 0; i < 2; ++i)
#pragma unroll
        for (int j = 0; j < 2; ++j)
          acc[i][j] = __builtin_amdgcn_mfma_f32_16x16x32_bf16(a[i], b[j], acc[i][j], 0, 0, 0);
    }
  }
  const size_t base = ((size_t)kc * H + h) * Cc * Cc;
#pragma unroll
  for (int i = 0; i < 2; ++i)
#pragma unroll
    for (int j = 0; j < 2; ++j)
#pragma unroll
      for (int r4 = 0; r4 < 4; ++r4) {
        const int ii = i0 + wm + i * 16 + (ln >> 4) * 4 + r4;
        const int jj = j0 + wn + j * 16 + (ln & 15);
        Sp[base + (size_t)ii * Cc + jj] = acc[i][j][r4];
      }
}

// ---------------------------------------------------------------------------
// Sum 4 K-partials, softmax over j, write fp32 probs (d_out) + bf16 copy (ws).
// ---------------------------------------------------------------------------
__global__ __launch_bounds__(256) void softmax_k(const float* __restrict__ Sp,
                                                 float* __restrict__ P,
                                                 unsigned short* __restrict__ Pb) {
  const int row = blockIdx.x, j = threadIdx.x;  // row = h*C + i
  const size_t stride = (size_t)H * Cc * Cc;
  const size_t base = (size_t)row * Cc + j;
  float s = Sp[base] + Sp[base + stride] + Sp[base + 2 * stride] + Sp[base + 3 * stride];
  float m = s;
#pragma unroll
  for (int o = 32; o > 0; o >>= 1) m = fmaxf(m, __shfl_xor(m, o));
  __shared__ float sm[4], ss[4];
  const int wid = j >> 6, lane = j & 63;
  if (lane == 0) sm[wid] = m;
  __syncthreads();
  m = fmaxf(fmaxf(sm[0], sm[1]), fmaxf(sm[2], sm[3]));
  float e = expf(s - m);
  float t = e;
#pragma unroll
  for (int o = 32; o > 0; o >>= 1) t += __shfl_xor(t, o);
  if (lane == 0) ss[wid] = t;
  __syncthreads();
  t = ss[0] + ss[1] + ss[2] + ss[3];
  const float p = e / t;
  P[base] = p;
  Pb[base] = f2b(p);
}

// ---------------------------------------------------------------------------
// PV: c[r,i,h,d] = sum_j P[h,i,j] * v[r,j,h,d], v pre-transposed as vT[n=h*64+d][token]
// Per block: fixed (h,r), 64(i) x 64(d), K=j=256 in 64-chunks.
// ---------------------------------------------------------------------------
__global__ __launch_bounds__(256) void pv_mfma(const unsigned short* __restrict__ P,
                                               const unsigned short* __restrict__ V,
                                               unsigned short* __restrict__ Co) {
  __shared__ unsigned short As[64 * 64];
  __shared__ unsigned short Bs[64 * 64];
  const int tid = threadIdx.x, wv = tid >> 6, ln = tid & 63;
  const int i0 = blockIdx.x * 64;
  const int r = blockIdx.y, h = blockIdx.z;
  const int wm = (wv & 1) * 32, wn = (wv >> 1) * 32;
  const int srow = ln >> 3, scol = (ln & 7) * 8;
  f32x4 acc[2][2] = {};
  for (int jc = 0; jc < 4; ++jc) {
    const int j0 = jc * 64;
    __syncthreads();
#pragma unroll
    for (int t = 0; t < 2; ++t) {
      const int ch = wv * 2 + t;
      const int row = ch * 8 + srow;
      ldst16(P + ((size_t)h * Cc + i0 + row) * Cc + j0 + scol, As + ch * 512 + ln * 8);
      ldst16(V + (size_t)(h * 64 + row) * M + r * Cc + j0 + scol, Bs + ch * 512 + ln * 8);
    }
    __syncthreads();
#pragma unroll
    for (int dk = 0; dk < 2; ++dk) {
      bf16x8 a[2], b[2];
#pragma unroll
      for (int i = 0; i < 2; ++i)
        a[i] = *(const bf16x8*)(As + (wm + i * 16 + (ln & 15)) * 64 + dk * 32 + (ln >> 4) * 8);
#pragma unroll
      for (int j = 0; j < 2; ++j)
        b[j] = *(const bf16x8*)(Bs + (wn + j * 16 + (ln & 15)) * 64 + dk * 32 + (ln >> 4) * 8);
#pragma unroll
      for (int i = 0; i < 2; ++i)
#pragma unroll
        for (int j = 0; j < 2; ++j)
          acc[i][j] = __builtin_amdgcn_mfma_f32_16x16x32_bf16(a[i], b[j], acc[i][j], 0, 0, 0);
    }
  }
#pragma unroll
  for (int i = 0; i < 2; ++i)
#pragma unroll
    for (int j = 0; j < 2; ++j)
#pragma unroll
      for (int r4 = 0; r4 < 4; ++r4) {
        const int mm = i0 + wm + i * 16 + (ln >> 4) * 4 + r4;
        const int nn = wn + j * 16 + (ln & 15);
        Co[((size_t)r * Cc + mm) * E + h * 64 + nn] = f2b(acc[i][j][r4]);
      }
}

// ---------------------------------------------------------------------------
extern "C" void kernel_launch(void* const* d_in, const int* in_sizes, int n_in,
                              void* d_out, int out_size, void* d_ws, size_t ws_size,
                              hipStream_t stream) {
  const float* x  = (const float*)d_in[0];
  const float* Wq = (const float*)d_in[1];
  const float* bq = (const float*)d_in[2];
  const float* Wk = (const float*)d_in[3];
  const float* bk = (const float*)d_in[4];
  const float* Wv = (const float*)d_in[5];
  const float* bv = (const float*)d_in[6];
  const float* Wo = (const float*)d_in[7];
  const float* bo = (const float*)d_in[8];
  float* out = (float*)d_out;             // (R,C,1,E)
  float* probs = out + TOK;               // (H,1,C,C)

  char* ws = (char*)d_ws;
  unsigned short* x_bf  = (unsigned short*)(ws);              // 50.3 MB
  unsigned short* q_bf  = (unsigned short*)(ws + 50331648);   // 50.3 MB
  unsigned short* k_bf  = (unsigned short*)(ws + 100663296);  // 50.3 MB
  unsigned short* vT_bf = (unsigned short*)(ws + 150994944);  // 50.3 MB  [N=768][M]
  unsigned short* Wq_bf = (unsigned short*)(ws + 201326592);  // 4 x 1.18 MB
  unsigned short* Wk_bf = Wq_bf + 589824;
  unsigned short* Wv_bf = Wk_bf + 589824;
  unsigned short* Wo_bf = Wv_bf + 589824;
  float* S_part         = (float*)(ws + 206045184);           // 12.6 MB (4 K-chunks)
  unsigned short* P_bf  = (unsigned short*)(ws + 218628096);  // 1.6 MB
  unsigned short* c_bf  = q_bf;  // q dead after qk_mfma

  const float scaling = 0.125f / sqrtf(128.f);  // Dk^-0.5 / sqrt(R)

  cvt_bf16<<<12288, 256, 0, stream>>>(x, x_bf, 3145728);
  cvt_bf16<<<288, 256, 0, stream>>>(Wq, Wq_bf, 73728);
  cvt_bf16<<<288, 256, 0, stream>>>(Wk, Wk_bf, 73728);
  cvt_bf16<<<288, 256, 0, stream>>>(Wv, Wv_bf, 73728);
  cvt_bf16<<<288, 256, 0, stream>>>(Wo, Wo_bf, 73728);

  dim3 gp(6, 256);  // N/128, M/128
  proj_mfma<0><<<gp, 256, 0, stream>>>(x_bf, Wq_bf, bq, q_bf, scaling);
  proj_mfma<0><<<gp, 256, 0, stream>>>(x_bf, Wk_bf, bk, k_bf, 1.0f);
  proj_mfma<1><<<gp, 256, 0, stream>>>(x_bf, Wv_bf, bv, vT_bf, 1.0f);

  qk_mfma<<<dim3(16, H, 4), 256, 0, stream>>>(q_bf, k_bf, S_part);
  softmax_k<<<H * Cc, 256, 0, stream>>>(S_part, probs, P_bf);
  pv_mfma<<<dim3(4, R, H), 256, 0, stream>>>(P_bf, vT_bf, c_bf);

  proj_mfma<2><<<gp, 256, 0, stream>>>(c_bf, Wo_bf, bo, out, 1.0f);
}